// Round 2
// baseline (388.548 us; speedup 1.0000x reference)
//
#include <hip/hip_runtime.h>
#include <hip/hip_bf16.h>
#include <stdint.h>

typedef float f32x4 __attribute__((ext_vector_type(4)));
typedef short s16x8 __attribute__((ext_vector_type(8)));

#define LN2F 0.6931471805599453f

static __device__ __forceinline__ f32x4 mfma16(s16x8 a, s16x8 b, f32x4 c) {
    return __builtin_amdgcn_mfma_f32_16x16x32_bf16(a, b, c, 0, 0, 0);
}

// ---------------- cos/sin table: [4096][32] ----------------
__global__ __launch_bounds__(256) void k_costab(float* __restrict__ ct, float* __restrict__ st) {
    int i = blockIdx.x * 256 + threadIdx.x;   // 131072 total
    int t = i >> 5, f = i & 31;
    float inv = powf(10000.0f, -(float)f / 32.0f);
    float a = (float)t * inv;
    ct[i] = cosf(a);
    st[i] = sinf(a);
}

// ---------------- fp32 -> bf16 convert + weight concat ----------------
__global__ __launch_bounds__(256) void k_convert(
        const float* __restrict__ x, const float* __restrict__ wq,
        const float* __restrict__ wk, const float* __restrict__ wv,
        const float* __restrict__ wo,
        __hip_bfloat16* __restrict__ xb, __hip_bfloat16* __restrict__ wb,
        __hip_bfloat16* __restrict__ wob) {
    size_t c = (size_t)blockIdx.x * 256 + threadIdx.x;
    if (c >= 1703936) return;
    size_t e = c * 4;
    const float* src;
    __hip_bfloat16* dst;
    if (e < 4194304) { src = x + e; dst = xb + e; }
    else if (e < 5242880) { src = wq + (e - 4194304); dst = wb + (e - 4194304); }
    else if (e < 5505024) { src = wk + (e - 5242880); dst = wb + (e - 4194304); }
    else if (e < 5767168) { src = wv + (e - 5505024); dst = wb + (e - 4194304); }
    else { src = wo + (e - 5767168); dst = wob + (e - 5767168); }
    float4 v = *(const float4*)src;
    ushort4 u;
    u.x = __bfloat16_as_ushort(__float2bfloat16(v.x));
    u.y = __bfloat16_as_ushort(__float2bfloat16(v.y));
    u.z = __bfloat16_as_ushort(__float2bfloat16(v.z));
    u.w = __bfloat16_as_ushort(__float2bfloat16(v.w));
    *(ushort4*)(void*)dst = u;
}

// ---------------- NT GEMM: C[M][N] = sum_k A[m][k]*B[n][k], bf16 in fp32 out ----------------
__global__ __launch_bounds__(256) void k_gemm_bt(
        const __hip_bfloat16* __restrict__ A, const __hip_bfloat16* __restrict__ B,
        float* __restrict__ C, int M, int N, int K) {
    __shared__ __hip_bfloat16 As[128][32];
    __shared__ __hip_bfloat16 Bs[128][32];
    int tid = threadIdx.x;
    int wave = tid >> 6, lane = tid & 63;
    int l15 = lane & 15, l4 = lane >> 4;
    int wr = (wave >> 1) * 64, wc = (wave & 1) * 64;
    int row0 = blockIdx.y * 128, col0 = blockIdx.x * 128;
    f32x4 acc[4][4] = {};
    int c0 = tid, c1 = tid + 256;
    int r0 = c0 >> 2, k0o = (c0 & 3) << 3;
    int r1 = c1 >> 2, k1o = (c1 & 3) << 3;
    for (int kb = 0; kb < K; kb += 32) {
        __syncthreads();
        *(s16x8*)(void*)&As[r0][k0o] = *(const s16x8*)(const void*)&A[(size_t)(row0 + r0) * K + kb + k0o];
        *(s16x8*)(void*)&As[r1][k1o] = *(const s16x8*)(const void*)&A[(size_t)(row0 + r1) * K + kb + k1o];
        *(s16x8*)(void*)&Bs[r0][k0o] = *(const s16x8*)(const void*)&B[(size_t)(col0 + r0) * K + kb + k0o];
        *(s16x8*)(void*)&Bs[r1][k1o] = *(const s16x8*)(const void*)&B[(size_t)(col0 + r1) * K + kb + k1o];
        __syncthreads();
        s16x8 af[4], bf[4];
#pragma unroll
        for (int m = 0; m < 4; m++) af[m] = *(const s16x8*)(const void*)&As[wr + m * 16 + l15][l4 * 8];
#pragma unroll
        for (int n = 0; n < 4; n++) bf[n] = *(const s16x8*)(const void*)&Bs[wc + n * 16 + l15][l4 * 8];
#pragma unroll
        for (int m = 0; m < 4; m++)
#pragma unroll
            for (int n = 0; n < 4; n++)
                acc[m][n] = mfma16(af[m], bf[n], acc[m][n]);
    }
#pragma unroll
    for (int m = 0; m < 4; m++)
#pragma unroll
        for (int n = 0; n < 4; n++)
#pragma unroll
            for (int r = 0; r < 4; r++)
                C[(size_t)(row0 + wr + m * 16 + l4 * 4 + r) * N + col0 + wc + n * 16 + l15] = acc[m][n][r];
}

// ---------------- RoPE + scatter ----------------
__global__ __launch_bounds__(256) void k_rope(
        const float* __restrict__ raw, const float* __restrict__ ct, const float* __restrict__ st,
        __hip_bfloat16* __restrict__ qr, __hip_bfloat16* __restrict__ kr,
        float* __restrict__ outK, float* __restrict__ outV) {
    int t = blockIdx.x;
    int tid = threadIdx.x;
    const float* r = raw + (size_t)t * 1536;
    for (int p = tid; p < 512; p += 256) {
        int head = p >> 5, f = p & 31;
        float a = r[head * 64 + f], b = r[head * 64 + f + 32];
        float c = ct[t * 32 + f], s = st[t * 32 + f];
        qr[(size_t)t * 1024 + head * 64 + f]      = __float2bfloat16(a * c - b * s);
        qr[(size_t)t * 1024 + head * 64 + f + 32] = __float2bfloat16(b * c + a * s);
    }
    if (tid < 128) {
        int kvh = tid >> 5, f = tid & 31;
        float a = r[1024 + kvh * 64 + f], b = r[1024 + kvh * 64 + f + 32];
        float c = ct[t * 32 + f], s = st[t * 32 + f];
        float ra = a * c - b * s, rb = b * c + a * s;
        kr[((size_t)kvh * 4096 + t) * 64 + f]      = __float2bfloat16(ra);
        kr[((size_t)kvh * 4096 + t) * 64 + f + 32] = __float2bfloat16(rb);
#pragma unroll
        for (int rep = 0; rep < 4; rep++) {
            outK[((size_t)(kvh * 4 + rep) * 4096 + t) * 64 + f]      = ra;
            outK[((size_t)(kvh * 4 + rep) * 4096 + t) * 64 + f + 32] = rb;
        }
    }
    {
        int kvh = tid >> 6, d = tid & 63;
        float v = r[1280 + tid];
#pragma unroll
        for (int rep = 0; rep < 4; rep++)
            outV[((size_t)(kvh * 4 + rep) * 4096 + t) * 64 + d] = v;
    }
}

// ---------------- V transpose: raw V cols -> vt[4][64][4096] bf16 ----------------
__global__ __launch_bounds__(256) void k_vtrans(const float* __restrict__ raw,
                                                __hip_bfloat16* __restrict__ vt) {
    int tt = blockIdx.x, kvh = blockIdx.y;
    int tid = threadIdx.x;
    for (int w = tid; w < 512; w += 256) {
        int d = w >> 3, t8 = (w & 7) << 3;
        s16x8 p;
#pragma unroll
        for (int j = 0; j < 8; j++)
            p[j] = __bfloat16_as_short(
                __float2bfloat16(raw[(size_t)(tt * 64 + t8 + j) * 1536 + 1280 + kvh * 64 + d]));
        *(s16x8*)(void*)&vt[((size_t)kvh * 64 + d) * 4096 + tt * 64 + t8] = p;
    }
}

// ---------------- ring attention (swapped-operand, lane-local softmax) ----------------
// grid (qt=16, ib=4, h=16), 256 thr; wave owns 16 q rows; kv tiles of 64 keys.
// S^T = mfma(K, Q): lane (l15,l4) holds S[key = n*16+l4*4+r][q = l15] -> softmax
// over keys is 15 in-lane fmax + 2 shfl_xor. No __syncthreads (wave-private P).
__global__ __launch_bounds__(256) void k_attn(
        const __hip_bfloat16* __restrict__ qr, const __hip_bfloat16* __restrict__ kr,
        const __hip_bfloat16* __restrict__ vt, __hip_bfloat16* __restrict__ ao) {
    const int qt = blockIdx.x, ib = blockIdx.y, h = blockIdx.z;
    const int kvh = h >> 2;
    const int tid = threadIdx.x, wave = tid >> 6, lane = tid & 63;
    const int l15 = lane & 15, l4 = lane >> 4;
    const int qbase = ib * 1024 + qt * 64 + wave * 16;
    __shared__ __hip_bfloat16 Pl[4][16][68];   // per-wave P^T, row stride 136B
    s16x8 qf[2];
#pragma unroll
    for (int kk = 0; kk < 2; kk++)
        qf[kk] = *(const s16x8*)(const void*)
            &qr[(size_t)(qbase + l15) * 1024 + h * 64 + kk * 32 + l4 * 8];
    f32x4 oacc[4] = {};
    float mrow = -1e30f, lrow = 0.0f;   // per-lane, q = l15, log2 domain
    const int kstart = (ib == 0) ? 0 : (ib - 1) * 1024;
    const int ntiles = (ib == 0) ? 16 : 32;
    const int nbias  = (ib == 0) ? 0 : 16;   // duplicated block => +ln2 => +1.0 in log2
    const __hip_bfloat16* Kh = kr + (size_t)kvh * 4096 * 64;
    const __hip_bfloat16* Vh = vt + (size_t)kvh * 64 * 4096;
    const float SC = 0.125f * 1.44269504088896340736f;  // scale * log2(e)
    for (int t = 0; t < ntiles; t++) {
        const int k0 = kstart + t * 64;
        f32x4 s[4] = {};
#pragma unroll
        for (int kk = 0; kk < 2; kk++) {
#pragma unroll
            for (int n = 0; n < 4; n++) {
                s16x8 kf = *(const s16x8*)(const void*)
                    &Kh[(size_t)(k0 + n * 16 + l15) * 64 + kk * 32 + l4 * 8];
                s[n] = mfma16(kf, qf[kk], s[n]);
            }
        }
        const float bias = (t < nbias) ? 1.0f : 0.0f;
        float v[16];
        float mx = -1e30f;
#pragma unroll
        for (int n = 0; n < 4; n++)
#pragma unroll
            for (int r = 0; r < 4; r++) {
                float z = s[n][r] * SC + bias;
                v[n * 4 + r] = z;
                mx = fmaxf(mx, z);
            }
        mx = fmaxf(mx, __shfl_xor(mx, 16));
        mx = fmaxf(mx, __shfl_xor(mx, 32));
        const float mnew = fmaxf(mrow, mx);
        const float alpha = exp2f(mrow - mnew);
        float sum = 0.0f;
        ushort4 pw[4];
#pragma unroll
        for (int n = 0; n < 4; n++) {
            float p0 = exp2f(v[n * 4 + 0] - mnew);
            float p1 = exp2f(v[n * 4 + 1] - mnew);
            float p2 = exp2f(v[n * 4 + 2] - mnew);
            float p3 = exp2f(v[n * 4 + 3] - mnew);
            sum += (p0 + p1) + (p2 + p3);
            pw[n].x = __bfloat16_as_ushort(__float2bfloat16(p0));
            pw[n].y = __bfloat16_as_ushort(__float2bfloat16(p1));
            pw[n].z = __bfloat16_as_ushort(__float2bfloat16(p2));
            pw[n].w = __bfloat16_as_ushort(__float2bfloat16(p3));
        }
        sum += __shfl_xor(sum, 16);
        sum += __shfl_xor(sum, 32);
        mrow = mnew;
        lrow = lrow * alpha + sum;
        // P^T -> LDS: Pl[q=l15][key n*16 + l4*4 .. +4], packed b64 writes
#pragma unroll
        for (int n = 0; n < 4; n++)
            *(ushort4*)(void*)&Pl[wave][l15][n * 16 + l4 * 4] = pw[n];
        // rescale O (rows q = l4*4+r need alpha from lane l4*4+r)
#pragma unroll
        for (int r = 0; r < 4; r++) {
            float ar = __shfl(alpha, l4 * 4 + r);
#pragma unroll
            for (int n = 0; n < 4; n++) oacc[n][r] *= ar;
        }
        // PV: pf (A) from LDS, vf (B) from vt
#pragma unroll
        for (int kk = 0; kk < 2; kk++) {
            s16x8 pf = *(const s16x8*)(const void*)&Pl[wave][l15][kk * 32 + l4 * 8];
#pragma unroll
            for (int n = 0; n < 4; n++) {
                s16x8 vf = *(const s16x8*)(const void*)
                    &Vh[(size_t)(n * 16 + l15) * 4096 + k0 + kk * 32 + l4 * 8];
                oacc[n] = mfma16(pf, vf, oacc[n]);
            }
        }
    }
#pragma unroll
    for (int r = 0; r < 4; r++) {
        float inv = 1.0f / __shfl(lrow, l4 * 4 + r);
#pragma unroll
        for (int n = 0; n < 4; n++)
            ao[(size_t)(qbase + l4 * 4 + r) * 1024 + h * 64 + n * 16 + l15] =
                __float2bfloat16(oacc[n][r] * inv);
    }
}

extern "C" void kernel_launch(void* const* d_in, const int* in_sizes, int n_in,
                              void* d_out, int out_size, void* d_ws, size_t ws_size,
                              hipStream_t stream) {
    const float* x  = (const float*)d_in[0];
    const float* wq = (const float*)d_in[1];
    const float* wk = (const float*)d_in[2];
    const float* wv = (const float*)d_in[3];
    const float* wo = (const float*)d_in[4];
    float* out0 = (float*)d_out;
    float* outK = out0 + 4194304;
    float* outV = out0 + 8388608;
    char* ws = (char*)d_ws;
    __hip_bfloat16* xb  = (__hip_bfloat16*)(ws + 0);          // 8 MB
    __hip_bfloat16* wb  = (__hip_bfloat16*)(ws + 8388608);    // 3 MB  (wq|wk|wv rows)
    __hip_bfloat16* wob = (__hip_bfloat16*)(ws + 11534336);   // 2 MB
    float* ct           = (float*)(ws + 13631488);            // 512 KB
    float* st           = (float*)(ws + 14155776);            // 512 KB
    float* raw          = (float*)(ws + 14680064);            // 25.2 MB [4096][1536] fp32
    __hip_bfloat16* qr  = (__hip_bfloat16*)(ws + 39845888);   // 8 MB
    __hip_bfloat16* kr  = (__hip_bfloat16*)(ws + 48234496);   // 2 MB [4][4096][64]
    __hip_bfloat16* vt  = (__hip_bfloat16*)(ws + 50331648);   // 2 MB [4][64][4096]
    __hip_bfloat16* ao  = (__hip_bfloat16*)(ws + 52428800);   // 8 MB

    hipLaunchKernelGGL(k_costab, dim3(512), dim3(256), 0, stream, ct, st);
    hipLaunchKernelGGL(k_convert, dim3(6656), dim3(256), 0, stream, x, wq, wk, wv, wo, xb, wb, wob);
    hipLaunchKernelGGL(k_gemm_bt, dim3(12, 32), dim3(256), 0, stream, xb, wb, raw, 4096, 1536, 1024);
    hipLaunchKernelGGL(k_rope, dim3(4096), dim3(256), 0, stream, raw, ct, st, qr, kr, outK, outV);
    hipLaunchKernelGGL(k_vtrans, dim3(64, 4), dim3(256), 0, stream, raw, vt);
    hipLaunchKernelGGL(k_attn, dim3(16, 4, 16), dim3(256), 0, stream, qr, kr, vt, ao);
    hipLaunchKernelGGL(k_gemm_bt, dim3(8, 32), dim3(256), 0, stream, ao, wob, out0, 4096, 1024, 1024);
}

// Round 4
// 278.726 us; speedup vs baseline: 1.3940x; 1.3940x over previous
//
#include <hip/hip_runtime.h>
#include <hip/hip_bf16.h>
#include <stdint.h>

typedef float f32x4 __attribute__((ext_vector_type(4)));
typedef float f32x16 __attribute__((ext_vector_type(16)));
typedef short s16x8 __attribute__((ext_vector_type(8)));

static __device__ __forceinline__ f32x4 mfma16(s16x8 a, s16x8 b, f32x4 c) {
    return __builtin_amdgcn_mfma_f32_16x16x32_bf16(a, b, c, 0, 0, 0);
}
static __device__ __forceinline__ f32x16 mfma32(s16x8 a, s16x8 b, f32x16 c) {
    return __builtin_amdgcn_mfma_f32_32x32x16_bf16(a, b, c, 0, 0, 0);
}

// ---------------- cos/sin table: [4096][32] ----------------
__global__ __launch_bounds__(256) void k_costab(float* __restrict__ ct, float* __restrict__ st) {
    int i = blockIdx.x * 256 + threadIdx.x;   // 131072 total
    int t = i >> 5, f = i & 31;
    float inv = powf(10000.0f, -(float)f / 32.0f);
    float a = (float)t * inv;
    ct[i] = cosf(a);
    st[i] = sinf(a);
}

// ---------------- fp32 -> bf16 convert + weight concat ----------------
__global__ __launch_bounds__(256) void k_convert(
        const float* __restrict__ x, const float* __restrict__ wq,
        const float* __restrict__ wk, const float* __restrict__ wv,
        const float* __restrict__ wo,
        __hip_bfloat16* __restrict__ xb, __hip_bfloat16* __restrict__ wb,
        __hip_bfloat16* __restrict__ wob) {
    size_t c = (size_t)blockIdx.x * 256 + threadIdx.x;
    if (c >= 1703936) return;
    size_t e = c * 4;
    const float* src;
    __hip_bfloat16* dst;
    if (e < 4194304) { src = x + e; dst = xb + e; }
    else if (e < 5242880) { src = wq + (e - 4194304); dst = wb + (e - 4194304); }
    else if (e < 5505024) { src = wk + (e - 5242880); dst = wb + (e - 4194304); }
    else if (e < 5767168) { src = wv + (e - 5505024); dst = wb + (e - 4194304); }
    else { src = wo + (e - 5767168); dst = wob + (e - 5767168); }
    float4 v = *(const float4*)src;
    ushort4 u;
    u.x = __bfloat16_as_ushort(__float2bfloat16(v.x));
    u.y = __bfloat16_as_ushort(__float2bfloat16(v.y));
    u.z = __bfloat16_as_ushort(__float2bfloat16(v.z));
    u.w = __bfloat16_as_ushort(__float2bfloat16(v.w));
    *(ushort4*)(void*)dst = u;
}

// ---------------- NT GEMM: C[M][N] = sum_k A[m][k]*B[n][k], bf16 in fp32 out ----------------
__global__ __launch_bounds__(256) void k_gemm_bt(
        const __hip_bfloat16* __restrict__ A, const __hip_bfloat16* __restrict__ B,
        float* __restrict__ C, int M, int N, int K) {
    __shared__ __hip_bfloat16 As[128][32];
    __shared__ __hip_bfloat16 Bs[128][32];
    int tid = threadIdx.x;
    int wave = tid >> 6, lane = tid & 63;
    int l15 = lane & 15, l4 = lane >> 4;
    int wr = (wave >> 1) * 64, wc = (wave & 1) * 64;
    int row0 = blockIdx.y * 128, col0 = blockIdx.x * 128;
    f32x4 acc[4][4] = {};
    int c0 = tid, c1 = tid + 256;
    int r0 = c0 >> 2, k0o = (c0 & 3) << 3;
    int r1 = c1 >> 2, k1o = (c1 & 3) << 3;
    for (int kb = 0; kb < K; kb += 32) {
        __syncthreads();
        *(s16x8*)(void*)&As[r0][k0o] = *(const s16x8*)(const void*)&A[(size_t)(row0 + r0) * K + kb + k0o];
        *(s16x8*)(void*)&As[r1][k1o] = *(const s16x8*)(const void*)&A[(size_t)(row0 + r1) * K + kb + k1o];
        *(s16x8*)(void*)&Bs[r0][k0o] = *(const s16x8*)(const void*)&B[(size_t)(col0 + r0) * K + kb + k0o];
        *(s16x8*)(void*)&Bs[r1][k1o] = *(const s16x8*)(const void*)&B[(size_t)(col0 + r1) * K + kb + k1o];
        __syncthreads();
        s16x8 af[4], bf[4];
#pragma unroll
        for (int m = 0; m < 4; m++) af[m] = *(const s16x8*)(const void*)&As[wr + m * 16 + l15][l4 * 8];
#pragma unroll
        for (int n = 0; n < 4; n++) bf[n] = *(const s16x8*)(const void*)&Bs[wc + n * 16 + l15][l4 * 8];
#pragma unroll
        for (int m = 0; m < 4; m++)
#pragma unroll
            for (int n = 0; n < 4; n++)
                acc[m][n] = mfma16(af[m], bf[n], acc[m][n]);
    }
#pragma unroll
    for (int m = 0; m < 4; m++)
#pragma unroll
        for (int n = 0; n < 4; n++)
#pragma unroll
            for (int r = 0; r < 4; r++)
                C[(size_t)(row0 + wr + m * 16 + l4 * 4 + r) * N + col0 + wc + n * 16 + l15] = acc[m][n][r];
}

// ---------------- RoPE + scatter (Q pre-scaled by 0.125*log2e for attention) ----------------
__global__ __launch_bounds__(256) void k_rope(
        const float* __restrict__ raw, const float* __restrict__ ct, const float* __restrict__ st,
        __hip_bfloat16* __restrict__ qr, __hip_bfloat16* __restrict__ kr,
        float* __restrict__ outK, float* __restrict__ outV) {
    const float SC = 0.125f * 1.44269504088896340736f;
    int t = blockIdx.x;
    int tid = threadIdx.x;
    const float* r = raw + (size_t)t * 1536;
    for (int p = tid; p < 512; p += 256) {
        int head = p >> 5, f = p & 31;
        float a = r[head * 64 + f], b = r[head * 64 + f + 32];
        float c = ct[t * 32 + f], s = st[t * 32 + f];
        qr[(size_t)t * 1024 + head * 64 + f]      = __float2bfloat16((a * c - b * s) * SC);
        qr[(size_t)t * 1024 + head * 64 + f + 32] = __float2bfloat16((b * c + a * s) * SC);
    }
    if (tid < 128) {
        int kvh = tid >> 5, f = tid & 31;
        float a = r[1024 + kvh * 64 + f], b = r[1024 + kvh * 64 + f + 32];
        float c = ct[t * 32 + f], s = st[t * 32 + f];
        float ra = a * c - b * s, rb = b * c + a * s;
        kr[((size_t)kvh * 4096 + t) * 64 + f]      = __float2bfloat16(ra);
        kr[((size_t)kvh * 4096 + t) * 64 + f + 32] = __float2bfloat16(rb);
#pragma unroll
        for (int rep = 0; rep < 4; rep++) {
            outK[((size_t)(kvh * 4 + rep) * 4096 + t) * 64 + f]      = ra;
            outK[((size_t)(kvh * 4 + rep) * 4096 + t) * 64 + f + 32] = rb;
        }
    }
    {
        int kvh = tid >> 6, d = tid & 63;
        float v = r[1280 + tid];
#pragma unroll
        for (int rep = 0; rep < 4; rep++)
            outV[((size_t)(kvh * 4 + rep) * 4096 + t) * 64 + d] = v;
    }
}

// ---------------- V transpose: raw V cols -> vt[4][64][4096] bf16 ----------------
__global__ __launch_bounds__(256) void k_vtrans(const float* __restrict__ raw,
                                                __hip_bfloat16* __restrict__ vt) {
    int tt = blockIdx.x, kvh = blockIdx.y;
    int tid = threadIdx.x;
    for (int w = tid; w < 512; w += 256) {
        int d = w >> 3, t8 = (w & 7) << 3;
        s16x8 p;
#pragma unroll
        for (int j = 0; j < 8; j++)
            p[j] = __bfloat16_as_short(
                __float2bfloat16(raw[(size_t)(tt * 64 + t8 + j) * 1536 + 1280 + kvh * 64 + d]));
        *(s16x8*)(void*)&vt[((size_t)kvh * 64 + d) * 4096 + tt * 64 + t8] = p;
    }
}

// ---------------- ring attention: 32x32 swapped-operand, P in registers ----------------
// grid (qt=8, ib=4, h=16), 256 thr. Wave owns 32 q rows; kv tiles of 64 keys.
// S^T[key][q] = mfma32(K, Q): lane (q=l31, hi) holds keys {ksub*32 + r0 + 8*r2 + 4*hi}.
// Softmax lane-local + 1 shfl_xor(32). P->bf16 in regs; A-frag assembly via 8
// shfl_xor(32) word exchanges with the partner half. Defer-max THR=8 (log2).
__global__ __launch_bounds__(256) void k_attn(
        const __hip_bfloat16* __restrict__ qr, const __hip_bfloat16* __restrict__ kr,
        const __hip_bfloat16* __restrict__ vt, __hip_bfloat16* __restrict__ ao) {
    const int qt = blockIdx.x, ib = blockIdx.y, h = blockIdx.z;
    const int kvh = h >> 2;
    const int tid = threadIdx.x, wave = tid >> 6, lane = tid & 63;
    const int l31 = lane & 31, hi = lane >> 5;
    const int q0 = ib * 1024 + qt * 128 + wave * 32;
    const __hip_bfloat16* Kh = kr + (size_t)kvh * 4096 * 64;
    const __hip_bfloat16* Vh = vt + (size_t)kvh * 64 * 4096;
    // Q B-fragments (pre-scaled): Q[q0+l31][dc*16 + hi*8 + j]
    s16x8 qf[4];
#pragma unroll
    for (int dc = 0; dc < 4; dc++)
        qf[dc] = *(const s16x8*)(const void*)
            &qr[(size_t)(q0 + l31) * 1024 + h * 64 + dc * 16 + hi * 8];
    f32x16 oacc[2] = {};                 // [dhalf]; rows q=(r&3)+8*(r>>2)+4*hi, col d=dhalf*32+l31
    float mrow = -1e30f, lrow = 0.0f;    // per q = l31 (identical in both halves), log2 domain
    const int kstart = (ib == 0) ? 0 : (ib - 1) * 1024;
    const int ntiles = (ib == 0) ? 16 : 32;
    const int nbias  = (ib == 0) ? 0 : 16;
    for (int t = 0; t < ntiles; t++) {
        const int k0 = kstart + t * 64;
        // QK^T (swapped): s[ksub][r] = S[key=ksub*32+(r&3)+8*(r>>2)+4*hi][q=l31]
        f32x16 s[2] = {};
#pragma unroll
        for (int dc = 0; dc < 4; dc++) {
#pragma unroll
            for (int ksub = 0; ksub < 2; ksub++) {
                s16x8 kf = *(const s16x8*)(const void*)
                    &Kh[(size_t)(k0 + ksub * 32 + l31) * 64 + dc * 16 + hi * 8];
                s[ksub] = mfma32(kf, qf[dc], s[ksub]);
            }
        }
        // V B-fragments (independent of P: overlap with softmax)
        s16x8 vfr[4][2];
#pragma unroll
        for (int c = 0; c < 4; c++)
#pragma unroll
            for (int dh = 0; dh < 2; dh++)
                vfr[c][dh] = *(const s16x8*)(const void*)
                    &Vh[(size_t)(dh * 32 + l31) * 4096 + k0 + c * 16 + hi * 8];
        const float bias = (t < nbias) ? 1.0f : 0.0f;
        // row max over 64 keys
        float mx = -1e30f;
#pragma unroll
        for (int ksub = 0; ksub < 2; ksub++)
#pragma unroll
            for (int r = 0; r < 16; r++) mx = fmaxf(mx, s[ksub][r]);
        mx = fmaxf(mx, __shfl_xor(mx, 32));
        mx += bias;
        // defer-max: rescale only when max grew by > 8 (log2)
        if (!__all(mx <= mrow + 8.0f)) {
            float mnew = fmaxf(mrow, mx);
            float alpha = exp2f(mrow - mnew);
            lrow *= alpha;
            mrow = mnew;
#pragma unroll
            for (int rr = 0; rr < 16; rr++) {
                int qrow = (rr & 3) + 8 * (rr >> 2) + 4 * hi;
                float ar = __shfl(alpha, qrow);
                oacc[0][rr] *= ar;
                oacc[1][rr] *= ar;
            }
        }
        const float mb = mrow - bias;
        // p = exp2(z - mb), sum, pack to bf16 words w[ksub][R][u] = regs {4R+2u, 4R+2u+1}
        float sum = 0.0f;
        uint32_t w[2][4][2];
#pragma unroll
        for (int ksub = 0; ksub < 2; ksub++) {
            float pv[16];
#pragma unroll
            for (int r = 0; r < 16; r++) {
                pv[r] = exp2f(s[ksub][r] - mb);
                sum += pv[r];
            }
#pragma unroll
            for (int R = 0; R < 4; R++)
#pragma unroll
                for (int u = 0; u < 2; u++) {
                    uint32_t lo = (uint32_t)__bfloat16_as_ushort(__float2bfloat16(pv[4 * R + 2 * u]));
                    uint32_t hiw = (uint32_t)__bfloat16_as_ushort(__float2bfloat16(pv[4 * R + 2 * u + 1]));
                    w[ksub][R][u] = lo | (hiw << 16);
                }
        }
        sum += __shfl_xor(sum, 32);
        lrow += sum;
        // PV: per k-chunk c (16 keys), assemble P A-frag via partner-half word exchange
#pragma unroll
        for (int c = 0; c < 4; c++) {
            const int ksub = c >> 1, cb = c & 1;
            uint32_t send0 = hi ? w[ksub][2 * cb][0] : w[ksub][2 * cb + 1][0];
            uint32_t send1 = hi ? w[ksub][2 * cb][1] : w[ksub][2 * cb + 1][1];
            uint32_t own0  = hi ? w[ksub][2 * cb + 1][0] : w[ksub][2 * cb][0];
            uint32_t own1  = hi ? w[ksub][2 * cb + 1][1] : w[ksub][2 * cb][1];
            uint32_t rcv0 = (uint32_t)__shfl_xor((int)send0, 32);
            uint32_t rcv1 = (uint32_t)__shfl_xor((int)send1, 32);
            union { uint32_t u[4]; s16x8 v; } pu;
            pu.u[0] = hi ? rcv0 : own0;   // half-0-held regs (keys c*16 + 8hi + 0..3)
            pu.u[1] = hi ? rcv1 : own1;
            pu.u[2] = hi ? own0 : rcv0;   // half-1-held regs (keys c*16 + 8hi + 4..7)
            pu.u[3] = hi ? own1 : rcv1;
#pragma unroll
            for (int dh = 0; dh < 2; dh++)
                oacc[dh] = mfma32(pu.v, vfr[c][dh], oacc[dh]);
        }
    }
    // epilogue: normalize rows and store
    float inv = 1.0f / lrow;
#pragma unroll
    for (int rr = 0; rr < 16; rr++) {
        int qrow = (rr & 3) + 8 * (rr >> 2) + 4 * hi;
        float iv = __shfl(inv, qrow);
#pragma unroll
        for (int dh = 0; dh < 2; dh++)
            ao[(size_t)(q0 + qrow) * 1024 + h * 64 + dh * 32 + l31] =
                __float2bfloat16(oacc[dh][rr] * iv);
    }
}

extern "C" void kernel_launch(void* const* d_in, const int* in_sizes, int n_in,
                              void* d_out, int out_size, void* d_ws, size_t ws_size,
                              hipStream_t stream) {
    const float* x  = (const float*)d_in[0];
    const float* wq = (const float*)d_in[1];
    const float* wk = (const float*)d_in[2];
    const float* wv = (const float*)d_in[3];
    const float* wo = (const float*)d_in[4];
    float* out0 = (float*)d_out;
    float* outK = out0 + 4194304;
    float* outV = out0 + 8388608;
    char* ws = (char*)d_ws;
    __hip_bfloat16* xb  = (__hip_bfloat16*)(ws + 0);          // 8 MB
    __hip_bfloat16* wb  = (__hip_bfloat16*)(ws + 8388608);    // 3 MB  (wq|wk|wv rows)
    __hip_bfloat16* wob = (__hip_bfloat16*)(ws + 11534336);   // 2 MB
    float* ct           = (float*)(ws + 13631488);            // 512 KB
    float* st           = (float*)(ws + 14155776);            // 512 KB
    float* raw          = (float*)(ws + 14680064);            // 25.2 MB [4096][1536] fp32
    __hip_bfloat16* qr  = (__hip_bfloat16*)(ws + 39845888);   // 8 MB (pre-scaled)
    __hip_bfloat16* kr  = (__hip_bfloat16*)(ws + 48234496);   // 2 MB [4][4096][64]
    __hip_bfloat16* vt  = (__hip_bfloat16*)(ws + 50331648);   // 2 MB [4][64][4096]
    __hip_bfloat16* ao  = (__hip_bfloat16*)(ws + 52428800);   // 8 MB

    hipLaunchKernelGGL(k_costab, dim3(512), dim3(256), 0, stream, ct, st);
    hipLaunchKernelGGL(k_convert, dim3(6656), dim3(256), 0, stream, x, wq, wk, wv, wo, xb, wb, wob);
    hipLaunchKernelGGL(k_gemm_bt, dim3(12, 32), dim3(256), 0, stream, xb, wb, raw, 4096, 1536, 1024);
    hipLaunchKernelGGL(k_rope, dim3(4096), dim3(256), 0, stream, raw, ct, st, qr, kr, outK, outV);
    hipLaunchKernelGGL(k_vtrans, dim3(64, 4), dim3(256), 0, stream, raw, vt);
    hipLaunchKernelGGL(k_attn, dim3(8, 4, 16), dim3(256), 0, stream, qr, kr, vt, ao);
    hipLaunchKernelGGL(k_gemm_bt, dim3(8, 32), dim3(256), 0, stream, ao, wob, out0, 4096, 1024, 1024);
}